// Round 1
// baseline (9223.746 us; speedup 1.0000x reference)
//
#include <hip/hip_runtime.h>

#define D 128
#define HEADS 4

// ---------- monotone float<->uint encoding for atomicMax on floats ----------
__device__ __forceinline__ unsigned enc_f32(float f) {
    unsigned u = __float_as_uint(f);
    return (u & 0x80000000u) ? ~u : (u | 0x80000000u);
}
__device__ __forceinline__ float dec_f32(unsigned u) {
    return __uint_as_float((u & 0x80000000u) ? (u ^ 0x80000000u) : ~u);
}

// ---------- GEMM: C[M,128] = A[M,128] @ W[128,128], f32 vector ----------
// buildmode=1: A-tile is gathered from the embedding tables (layer-1 concat fused)
__global__ __launch_bounds__(256) void gemm64(
    const float* __restrict__ A, const float* __restrict__ W,
    float* __restrict__ C, int buildmode,
    const int* __restrict__ ent_feature, const float* __restrict__ gw,
    const float* __restrict__ aw, const float* __restrict__ lw,
    const float* __restrict__ idemb, int num_ent)
{
    __shared__ float4 sA4[64 * 32];   // 64 rows x 128 cols = 32 KB
    const long row0 = (long)blockIdx.x * 64;
    const int t = threadIdx.x;

    if (!buildmode) {
        const float4* A4 = (const float4*)(A + row0 * D);
        #pragma unroll
        for (int i = 0; i < 8; ++i) sA4[t + 256 * i] = A4[t + 256 * i];
    } else {
        #pragma unroll
        for (int i = 0; i < 8; ++i) {
            int idx = t + 256 * i;          // float4 index within tile
            long row = row0 + (idx >> 5);
            int q = idx & 31;
            const float* srcp;
            if (row < num_ent)               srcp = idemb + row * D;
            else if (row < 2L * num_ent)     srcp = gw + (long)ent_feature[(row - num_ent) * 3 + 0] * D;
            else if (row < 3L * num_ent)     srcp = aw + (long)ent_feature[(row - 2L * num_ent) * 3 + 1] * D;
            else                             srcp = lw + (long)ent_feature[(row - 3L * num_ent) * 3 + 2] * D;
            sA4[idx] = ((const float4*)srcp)[q];
        }
    }
    __syncthreads();

    const int tx = t & 31;   // cols [tx*4, tx*4+4)
    const int ty = t >> 5;   // rows [ty*8, ty*8+8)
    float acc[8][4];
    #pragma unroll
    for (int r = 0; r < 8; ++r)
        #pragma unroll
        for (int c = 0; c < 4; ++c) acc[r][c] = 0.f;

    const float4* W4 = (const float4*)W;
    #pragma unroll 2
    for (int kc = 0; kc < 32; ++kc) {
        float4 w0 = W4[(kc * 4 + 0) * 32 + tx];
        float4 w1 = W4[(kc * 4 + 1) * 32 + tx];
        float4 w2 = W4[(kc * 4 + 2) * 32 + tx];
        float4 w3 = W4[(kc * 4 + 3) * 32 + tx];
        #pragma unroll
        for (int r = 0; r < 8; ++r) {
            float4 a = sA4[(ty * 8 + r) * 32 + kc];
            acc[r][0] = fmaf(a.x, w0.x, fmaf(a.y, w1.x, fmaf(a.z, w2.x, fmaf(a.w, w3.x, acc[r][0]))));
            acc[r][1] = fmaf(a.x, w0.y, fmaf(a.y, w1.y, fmaf(a.z, w2.y, fmaf(a.w, w3.y, acc[r][1]))));
            acc[r][2] = fmaf(a.x, w0.z, fmaf(a.y, w1.z, fmaf(a.z, w2.z, fmaf(a.w, w3.z, acc[r][2]))));
            acc[r][3] = fmaf(a.x, w0.w, fmaf(a.y, w1.w, fmaf(a.z, w2.w, fmaf(a.w, w3.w, acc[r][3]))));
        }
    }

    float4* C4 = (float4*)(C + row0 * D);
    #pragma unroll
    for (int r = 0; r < 8; ++r)
        C4[(ty * 8 + r) * 32 + tx] = make_float4(acc[r][0], acc[r][1], acc[r][2], acc[r][3]);
}

// ---------- tiny GEMM: out[rows,128] = R[rows,128] @ W[128,128] ----------
__global__ void small_gemm(const float* __restrict__ R, const float* __restrict__ W,
                           float* __restrict__ out)
{
    int r = blockIdx.x, c = threadIdx.x;
    float s = 0.f;
    for (int k = 0; k < D; ++k) s = fmaf(R[r * D + k], W[k * D + c], s);
    out[r * D + c] = s;
}

// ---------- edge pass B: scores + segment max ----------
// 8 lanes per edge; lane covers 16 consecutive floats (= half a head)
__global__ __launch_bounds__(256) void edge_score(
    const int* __restrict__ src, const int* __restrict__ dst, const int* __restrict__ etype,
    const float* __restrict__ xW, const float* __restrict__ rW, const float* __restrict__ att,
    float* __restrict__ score, unsigned* __restrict__ segmax, int E_)
{
    int t = blockIdx.x * 256 + threadIdx.x;
    int e = t >> 3;
    if (e >= E_) return;
    int part = t & 7;
    int s = src[e], d = dst[e], r = etype[e];
    int head = part >> 1;
    int off = part * 16;

    const float4* q4 = (const float4*)(xW + (long)d * D + off);
    const float4* m4 = (const float4*)(xW + (long)s * D + off);
    const float4* r4 = (const float4*)(rW + (long)r * D + off);
    const float4* aq = (const float4*)(att + head * 64 + (part & 1) * 16);
    const float4* am = (const float4*)(att + head * 64 + 32 + (part & 1) * 16);

    float p = 0.f;
    #pragma unroll
    for (int j = 0; j < 4; ++j) {
        float4 q = q4[j], m = m4[j], rr = r4[j], a = aq[j], b = am[j];
        p = fmaf(q.x, a.x, fmaf(q.y, a.y, fmaf(q.z, a.z, fmaf(q.w, a.w, p))));
        float mx = m.x + rr.x, my = m.y + rr.y, mz = m.z + rr.z, mw = m.w + rr.w;
        p = fmaf(mx, b.x, fmaf(my, b.y, fmaf(mz, b.z, fmaf(mw, b.w, p))));
    }
    p += __shfl_xor(p, 1);
    float sc = p > 0.f ? p : 0.2f * p;   // leaky_relu(., 0.2)
    if ((part & 1) == 0) {
        score[(long)e * HEADS + head] = sc;
        atomicMax(&segmax[(long)d * HEADS + head], enc_f32(sc));
    }
}

// ---------- edge pass C: e = exp(sc - max); segsum += e; acc[dst] += e * m ----------
__global__ __launch_bounds__(256) void edge_accum(
    const int* __restrict__ src, const int* __restrict__ dst, const int* __restrict__ etype,
    const float* __restrict__ xW, const float* __restrict__ rW,
    const float* __restrict__ score, const unsigned* __restrict__ segmax,
    float* __restrict__ segsum, float* __restrict__ acc, int E_)
{
    int t = blockIdx.x * 256 + threadIdx.x;
    int e = t >> 3;
    if (e >= E_) return;
    int part = t & 7;
    int s = src[e], d = dst[e], r = etype[e];
    int head = part >> 1;
    int off = part * 16;

    float sc = score[(long)e * HEADS + head];
    float mx = dec_f32(segmax[(long)d * HEADS + head]);
    float eh = expf(sc - mx);
    if ((part & 1) == 0) atomicAdd(&segsum[(long)d * HEADS + head], eh);

    const float4* m4 = (const float4*)(xW + (long)s * D + off);
    const float4* r4 = (const float4*)(rW + (long)r * D + off);
    float* ap = acc + (long)d * D + off;
    #pragma unroll
    for (int j = 0; j < 4; ++j) {
        float4 m = m4[j], rr = r4[j];
        atomicAdd(ap + j * 4 + 0, eh * (m.x + rr.x));
        atomicAdd(ap + j * 4 + 1, eh * (m.y + rr.y));
        atomicAdd(ap + j * 4 + 2, eh * (m.z + rr.z));
        atomicAdd(ap + j * 4 + 3, eh * (m.w + rr.w));
    }
}

// ---------- normalize + tanh ----------
__global__ __launch_bounds__(256) void norm_tanh(
    const float* __restrict__ acc, const float* __restrict__ segsum,
    float* __restrict__ out, long total4)
{
    long idx = (long)blockIdx.x * 256 + threadIdx.x;
    if (idx >= total4) return;
    long row = idx >> 5;
    int q = (int)(idx & 31);
    int head = q >> 3;
    float s = segsum[row * HEADS + head] + 1e-16f;
    float inv = 1.0f / s;
    float4 a = ((const float4*)acc)[idx];
    float4 o;
    o.x = tanhf(a.x * inv);
    o.y = tanhf(a.y * inv);
    o.z = tanhf(a.z * inv);
    o.w = tanhf(a.w * inv);
    ((float4*)out)[idx] = o;
}

// ---------- row gather ----------
__global__ void gather_rows(const int* __restrict__ idx, const float* __restrict__ srcm,
                            float* __restrict__ dstm, int b)
{
    long i = (long)blockIdx.x * 256 + threadIdx.x;
    if (i >= (long)b * 32) return;
    long row = i >> 5;
    int q = (int)(i & 31);
    ((float4*)dstm)[i] = ((const float4*)(srcm + (long)idx[row] * D))[q];
}

extern "C" void kernel_launch(void* const* d_in, const int* in_sizes, int n_in,
                              void* d_out, int out_size, void* d_ws, size_t ws_size,
                              hipStream_t stream)
{
    const int*   sub        = (const int*)d_in[0];
    const int*   rel        = (const int*)d_in[1];
    const int*   edge_index = (const int*)d_in[2];
    const int*   edge_type  = (const int*)d_in[3];
    const int*   ent_feat   = (const int*)d_in[4];
    const float* gw         = (const float*)d_in[5];
    const float* aw         = (const float*)d_in[6];
    const float* lw         = (const float*)d_in[7];
    const float* idemb      = (const float*)d_in[8];
    const float* init_rel   = (const float*)d_in[9];
    const float* W1         = (const float*)d_in[10];
    const float* Wr1        = (const float*)d_in[11];
    const float* att1       = (const float*)d_in[12];
    const float* W2         = (const float*)d_in[13];
    const float* Wr2        = (const float*)d_in[14];
    const float* att2       = (const float*)d_in[15];

    const int  Bn      = in_sizes[0];
    const int  E_      = in_sizes[3];
    const int  num_ent = in_sizes[4] / 3;
    const long Nn      = 4L * num_ent;
    const int  nrel    = in_sizes[9] / D;

    const int* srcp = edge_index;
    const int* dstp = edge_index + E_;

    float* out_sub = (float*)d_out;
    float* out_rel = out_sub + (long)Bn * D;
    float* out_x   = out_rel + (long)Bn * D;   // N x 128 region, also used as scratch

    float*    Xbuf   = (float*)d_ws;                    // N x 128
    float*    scoreb = Xbuf + Nn * D;                   // E x 4
    unsigned* segmax = (unsigned*)(scoreb + (long)E_ * HEADS);  // N x 4
    float*    segsum = (float*)(segmax + Nn * HEADS);   // N x 4
    float*    rWb    = segsum + Nn * HEADS;             // nrel x 128
    float*    r1     = rWb + (long)nrel * D;
    float*    r2     = r1 + (long)nrel * D;

    dim3 blk(256);
    int gemm_blocks = (int)(Nn / 64);
    int edge_blocks = (int)((8L * E_ + 255) / 256);
    int nt_blocks   = (int)((Nn * 32 + 255) / 256);
    int gat_blocks  = (int)(((long)Bn * 32 + 255) / 256);

    // ---------------- Layer 1 ----------------
    gemm64<<<gemm_blocks, blk, 0, stream>>>(nullptr, W1, out_x, 1,
                                            ent_feat, gw, aw, lw, idemb, num_ent);
    small_gemm<<<nrel, D, 0, stream>>>(init_rel, W1, rWb);
    small_gemm<<<nrel, D, 0, stream>>>(init_rel, Wr1, r1);
    hipMemsetAsync(segmax, 0, Nn * HEADS * sizeof(unsigned), stream);
    edge_score<<<edge_blocks, blk, 0, stream>>>(srcp, dstp, edge_type, out_x, rWb, att1,
                                                scoreb, segmax, E_);
    hipMemsetAsync(segsum, 0, Nn * HEADS * sizeof(float), stream);
    hipMemsetAsync(Xbuf, 0, Nn * D * sizeof(float), stream);
    edge_accum<<<edge_blocks, blk, 0, stream>>>(srcp, dstp, edge_type, out_x, rWb,
                                                scoreb, segmax, segsum, Xbuf, E_);
    norm_tanh<<<nt_blocks, blk, 0, stream>>>(Xbuf, segsum, out_x, Nn * 32);

    // ---------------- Layer 2 ----------------
    gemm64<<<gemm_blocks, blk, 0, stream>>>(out_x, W2, Xbuf, 0,
                                            nullptr, nullptr, nullptr, nullptr, nullptr, num_ent);
    small_gemm<<<nrel, D, 0, stream>>>(r1, W2, rWb);
    small_gemm<<<nrel, D, 0, stream>>>(r1, Wr2, r2);
    hipMemsetAsync(segmax, 0, Nn * HEADS * sizeof(unsigned), stream);
    edge_score<<<edge_blocks, blk, 0, stream>>>(srcp, dstp, edge_type, Xbuf, rWb, att2,
                                                scoreb, segmax, E_);
    hipMemsetAsync(segsum, 0, Nn * HEADS * sizeof(float), stream);
    hipMemsetAsync(out_x, 0, Nn * D * sizeof(float), stream);
    edge_accum<<<edge_blocks, blk, 0, stream>>>(srcp, dstp, edge_type, Xbuf, rWb,
                                                scoreb, segmax, segsum, out_x, E_);
    norm_tanh<<<nt_blocks, blk, 0, stream>>>(out_x, segsum, out_x, Nn * 32);

    // ---------------- outputs ----------------
    gather_rows<<<gat_blocks, blk, 0, stream>>>(sub, out_x, out_sub, Bn);
    gather_rows<<<gat_blocks, blk, 0, stream>>>(rel, r2, out_rel, Bn);
}

// Round 2
// 581.192 us; speedup vs baseline: 15.8704x; 15.8704x over previous
//
#include <hip/hip_runtime.h>

#define D 128
#define HEADS 4

// ---------- GEMM: C[M,128] = A[M,128] @ W[128,128], f32 vector ----------
// buildmode=1: A-tile is gathered from the embedding tables (layer-1 concat fused)
__global__ __launch_bounds__(256) void gemm64(
    const float* __restrict__ A, const float* __restrict__ W,
    float* __restrict__ C, int buildmode,
    const int* __restrict__ ent_feature, const float* __restrict__ gw,
    const float* __restrict__ aw, const float* __restrict__ lw,
    const float* __restrict__ idemb, int num_ent)
{
    __shared__ float4 sA4[64 * 32];   // 64 rows x 128 cols = 32 KB
    const long row0 = (long)blockIdx.x * 64;
    const int t = threadIdx.x;

    if (!buildmode) {
        const float4* A4 = (const float4*)(A + row0 * D);
        #pragma unroll
        for (int i = 0; i < 8; ++i) sA4[t + 256 * i] = A4[t + 256 * i];
    } else {
        #pragma unroll
        for (int i = 0; i < 8; ++i) {
            int idx = t + 256 * i;          // float4 index within tile
            long row = row0 + (idx >> 5);
            int q = idx & 31;
            const float* srcp;
            if (row < num_ent)               srcp = idemb + row * D;
            else if (row < 2L * num_ent)     srcp = gw + (long)ent_feature[(row - num_ent) * 3 + 0] * D;
            else if (row < 3L * num_ent)     srcp = aw + (long)ent_feature[(row - 2L * num_ent) * 3 + 1] * D;
            else                             srcp = lw + (long)ent_feature[(row - 3L * num_ent) * 3 + 2] * D;
            sA4[idx] = ((const float4*)srcp)[q];
        }
    }
    __syncthreads();

    const int tx = t & 31;   // cols [tx*4, tx*4+4)
    const int ty = t >> 5;   // rows [ty*8, ty*8+8)
    float acc[8][4];
    #pragma unroll
    for (int r = 0; r < 8; ++r)
        #pragma unroll
        for (int c = 0; c < 4; ++c) acc[r][c] = 0.f;

    const float4* W4 = (const float4*)W;
    #pragma unroll 2
    for (int kc = 0; kc < 32; ++kc) {
        float4 w0 = W4[(kc * 4 + 0) * 32 + tx];
        float4 w1 = W4[(kc * 4 + 1) * 32 + tx];
        float4 w2 = W4[(kc * 4 + 2) * 32 + tx];
        float4 w3 = W4[(kc * 4 + 3) * 32 + tx];
        #pragma unroll
        for (int r = 0; r < 8; ++r) {
            float4 a = sA4[(ty * 8 + r) * 32 + kc];
            acc[r][0] = fmaf(a.x, w0.x, fmaf(a.y, w1.x, fmaf(a.z, w2.x, fmaf(a.w, w3.x, acc[r][0]))));
            acc[r][1] = fmaf(a.x, w0.y, fmaf(a.y, w1.y, fmaf(a.z, w2.y, fmaf(a.w, w3.y, acc[r][1]))));
            acc[r][2] = fmaf(a.x, w0.z, fmaf(a.y, w1.z, fmaf(a.z, w2.z, fmaf(a.w, w3.z, acc[r][2]))));
            acc[r][3] = fmaf(a.x, w0.w, fmaf(a.y, w1.w, fmaf(a.z, w2.w, fmaf(a.w, w3.w, acc[r][3]))));
        }
    }

    float4* C4 = (float4*)(C + row0 * D);
    #pragma unroll
    for (int r = 0; r < 8; ++r)
        C4[(ty * 8 + r) * 32 + tx] = make_float4(acc[r][0], acc[r][1], acc[r][2], acc[r][3]);
}

// ---------- tiny GEMM: out[rows,128] = R[rows,128] @ W[128,128] ----------
__global__ void small_gemm(const float* __restrict__ R, const float* __restrict__ W,
                           float* __restrict__ out)
{
    int r = blockIdx.x, c = threadIdx.x;
    float s = 0.f;
    for (int k = 0; k < D; ++k) s = fmaf(R[r * D + k], W[k * D + c], s);
    out[r * D + c] = s;
}

// ---------- CSR build ----------
__global__ __launch_bounds__(256) void hist_deg(const int* __restrict__ dst,
                                                int* __restrict__ deg, int E_)
{
    int i = blockIdx.x * 256 + threadIdx.x;
    if (i < E_) atomicAdd(&deg[dst[i]], 1);
}

// per-block (1024-elem chunk) exclusive scan; writes local-exclusive offs + block total
__global__ __launch_bounds__(256) void scan_local(const int* __restrict__ deg,
                                                  int* __restrict__ offs,
                                                  int* __restrict__ partial, int n)
{
    __shared__ int lds[256];
    int b = blockIdx.x, t = threadIdx.x;
    int base = b * 1024;
    int v[4]; int s = 0;
    #pragma unroll
    for (int j = 0; j < 4; ++j) {
        int idx = base + t * 4 + j;
        v[j] = idx < n ? deg[idx] : 0;
        s += v[j];
    }
    lds[t] = s;
    __syncthreads();
    int mysum = s;
    for (int off = 1; off < 256; off <<= 1) {
        int o = t >= off ? lds[t - off] : 0;
        __syncthreads();
        lds[t] += o;
        __syncthreads();
    }
    int excl = lds[t] - mysum;
    if (t == 255) partial[b] = lds[255];
    int run = excl;
    #pragma unroll
    for (int j = 0; j < 4; ++j) {
        int idx = base + t * 4 + j;
        if (idx < n) offs[idx] = run;
        run += v[j];
    }
}

__global__ void scan_partials(int* __restrict__ partial, int nb, int* __restrict__ offs, int n)
{
    if (threadIdx.x == 0 && blockIdx.x == 0) {
        int run = 0;
        for (int i = 0; i < nb; ++i) { int v = partial[i]; partial[i] = run; run += v; }
        offs[n] = run;
    }
}

__global__ __launch_bounds__(256) void scan_add(int* __restrict__ offs,
                                                const int* __restrict__ partial, int n)
{
    int idx = blockIdx.x * 256 + threadIdx.x;
    if (idx < n) offs[idx] += partial[idx >> 10];
}

// scatter: sorted[offs[d] + cursor[d]++] = src | (etype<<18)
__global__ __launch_bounds__(256) void scatter_edges(
    const int* __restrict__ src, const int* __restrict__ dst, const int* __restrict__ etype,
    const int* __restrict__ offs, int* __restrict__ cursor,
    int* __restrict__ sorted, int E_)
{
    int i = blockIdx.x * 256 + threadIdx.x;
    if (i >= E_) return;
    int d = dst[i];
    int pos = offs[d] + atomicAdd(&cursor[d], 1);
    sorted[pos] = src[i] | (etype[i] << 18);
}

// ---------- fused per-node aggregation: score + online softmax + accum + tanh ----------
// one 64-lane wave per dst node; lane l covers floats [2l, 2l+1]; head = l>>4
__global__ __launch_bounds__(256) void agg_node(
    const int* __restrict__ offs, const int* __restrict__ sedge,
    const float* __restrict__ xW, const float* __restrict__ rW,
    const float* __restrict__ att, float* __restrict__ outx, int Nn)
{
    int wid = threadIdx.x >> 6;
    int lane = threadIdx.x & 63;
    long node = (long)blockIdx.x * 4 + wid;
    if (node >= Nn) return;
    int h = lane >> 4;     // head
    int w = lane & 15;     // position within head (covers 2 floats of 32)

    float2 aq = *(const float2*)(att + h * 64 + 2 * w);
    float2 am = *(const float2*)(att + h * 64 + 32 + 2 * w);
    float2 q  = *(const float2*)(xW + node * D + 2 * lane);

    float qd = q.x * aq.x + q.y * aq.y;
    qd += __shfl_xor(qd, 1);
    qd += __shfl_xor(qd, 2);
    qd += __shfl_xor(qd, 4);
    qd += __shfl_xor(qd, 8);

    int e0 = offs[node], e1 = offs[node + 1];
    float mrun = -INFINITY, srun = 0.f;
    float ax = 0.f, ay = 0.f;

    for (int i = e0; i < e1; ++i) {
        int p  = sedge[i];
        int s  = p & 0x3FFFF;
        int et = p >> 18;
        float2 mv = *(const float2*)(xW + (long)s * D + 2 * lane);
        float2 rv = *(const float2*)(rW + (long)et * D + 2 * lane);
        mv.x += rv.x; mv.y += rv.y;
        float md = mv.x * am.x + mv.y * am.y;
        md += __shfl_xor(md, 1);
        md += __shfl_xor(md, 2);
        md += __shfl_xor(md, 4);
        md += __shfl_xor(md, 8);
        float sc = qd + md;
        sc = sc > 0.f ? sc : 0.2f * sc;          // leaky_relu 0.2
        float nm = fmaxf(mrun, sc);
        float scale = __expf(mrun - nm);         // first iter: exp(-inf)=0
        float we = __expf(sc - nm);
        srun = srun * scale + we;
        ax = ax * scale + we * mv.x;
        ay = ay * scale + we * mv.y;
        mrun = nm;
    }
    float inv = 1.0f / (srun + 1e-16f);
    float2 o;
    o.x = tanhf(ax * inv);
    o.y = tanhf(ay * inv);
    *(float2*)(outx + node * D + 2 * lane) = o;
}

// ---------- row gather ----------
__global__ void gather_rows(const int* __restrict__ idx, const float* __restrict__ srcm,
                            float* __restrict__ dstm, int b)
{
    long i = (long)blockIdx.x * 256 + threadIdx.x;
    if (i >= (long)b * 32) return;
    long row = i >> 5;
    int q = (int)(i & 31);
    ((float4*)dstm)[i] = ((const float4*)(srcm + (long)idx[row] * D))[q];
}

extern "C" void kernel_launch(void* const* d_in, const int* in_sizes, int n_in,
                              void* d_out, int out_size, void* d_ws, size_t ws_size,
                              hipStream_t stream)
{
    const int*   sub        = (const int*)d_in[0];
    const int*   rel        = (const int*)d_in[1];
    const int*   edge_index = (const int*)d_in[2];
    const int*   edge_type  = (const int*)d_in[3];
    const int*   ent_feat   = (const int*)d_in[4];
    const float* gw         = (const float*)d_in[5];
    const float* aw         = (const float*)d_in[6];
    const float* lw         = (const float*)d_in[7];
    const float* idemb      = (const float*)d_in[8];
    const float* init_rel   = (const float*)d_in[9];
    const float* W1         = (const float*)d_in[10];
    const float* Wr1        = (const float*)d_in[11];
    const float* att1       = (const float*)d_in[12];
    const float* W2         = (const float*)d_in[13];
    const float* Wr2        = (const float*)d_in[14];
    const float* att2       = (const float*)d_in[15];

    const int  Bn      = in_sizes[0];
    const int  E_      = in_sizes[3];
    const int  num_ent = in_sizes[4] / 3;
    const long Nn      = 4L * num_ent;
    const int  nrel    = in_sizes[9] / D;

    const int* srcp = edge_index;
    const int* dstp = edge_index + E_;

    float* out_sub = (float*)d_out;
    float* out_rel = out_sub + (long)Bn * D;
    float* out_x   = out_rel + (long)Bn * D;   // N x 128 final x

    float* Xbuf   = (float*)d_ws;              // N x 128 (xW scratch)
    int*   offs   = (int*)(Xbuf + Nn * D);     // N+1
    int*   deg    = offs + (Nn + 1);           // N (also cursor)
    int*   sorted = deg + Nn;                  // E
    int*   partial= sorted + E_;               // <=1024 block partials
    float* rWb    = (float*)(partial + 1024);  // nrel x 128
    float* r1     = rWb + (long)nrel * D;
    float* r2     = r1 + (long)nrel * D;

    dim3 blk(256);
    int gemm_blocks  = (int)(Nn / 64);
    int e_blocks     = (E_ + 255) / 256;
    int agg_blocks   = (int)((Nn + 3) / 4);
    int gat_blocks   = (int)(((long)Bn * 32 + 255) / 256);
    int scan_blocks  = (int)((Nn + 1023) / 1024);
    int sadd_blocks  = (int)((Nn + 255) / 256);

    // ---------------- CSR build (by dst) ----------------
    hipMemsetAsync(deg, 0, Nn * sizeof(int), stream);
    hist_deg<<<e_blocks, blk, 0, stream>>>(dstp, deg, E_);
    scan_local<<<scan_blocks, blk, 0, stream>>>(deg, offs, partial, (int)Nn);
    scan_partials<<<1, 64, 0, stream>>>(partial, scan_blocks, offs, (int)Nn);
    scan_add<<<sadd_blocks, blk, 0, stream>>>(offs, partial, (int)Nn);
    hipMemsetAsync(deg, 0, Nn * sizeof(int), stream);   // reuse as cursor
    scatter_edges<<<e_blocks, blk, 0, stream>>>(srcp, dstp, edge_type, offs, deg, sorted, E_);

    // ---------------- Layer 1 ----------------
    gemm64<<<gemm_blocks, blk, 0, stream>>>(nullptr, W1, Xbuf, 1,
                                            ent_feat, gw, aw, lw, idemb, num_ent);
    small_gemm<<<nrel, D, 0, stream>>>(init_rel, W1, rWb);
    small_gemm<<<nrel, D, 0, stream>>>(init_rel, Wr1, r1);
    agg_node<<<agg_blocks, blk, 0, stream>>>(offs, sorted, Xbuf, rWb, att1, out_x, (int)Nn);

    // ---------------- Layer 2 ----------------
    gemm64<<<gemm_blocks, blk, 0, stream>>>(out_x, W2, Xbuf, 0,
                                            nullptr, nullptr, nullptr, nullptr, nullptr, num_ent);
    small_gemm<<<nrel, D, 0, stream>>>(r1, W2, rWb);
    small_gemm<<<nrel, D, 0, stream>>>(r1, Wr2, r2);
    agg_node<<<agg_blocks, blk, 0, stream>>>(offs, sorted, Xbuf, rWb, att2, out_x, (int)Nn);

    // ---------------- outputs ----------------
    gather_rows<<<gat_blocks, blk, 0, stream>>>(sub, out_x, out_sub, Bn);
    gather_rows<<<gat_blocks, blk, 0, stream>>>(rel, r2, out_rel, Bn);
}

// Round 3
// 422.169 us; speedup vs baseline: 21.8485x; 1.3767x over previous
//
#include <hip/hip_runtime.h>

#define D 128
#define HEADS 4

typedef __attribute__((ext_vector_type(8))) short short8;
typedef __attribute__((ext_vector_type(4))) float f32x4;

// f32 -> bf16 (round to nearest even), bit pattern in short
__device__ __forceinline__ short f2b(float f) {
    unsigned u = __float_as_uint(f);
    unsigned r = (u + 0x7FFFu + ((u >> 16) & 1u)) >> 16;
    return (short)r;
}

// ---------- W transpose to bf16: Wt[n][k] = bf16(W[k][n]) ----------
// grid 256 x 128 threads: blocks 0..127 -> Wt1, 128..255 -> Wt2
__global__ void wtrans(const float* __restrict__ W1, const float* __restrict__ W2,
                       short* __restrict__ Wt1, short* __restrict__ Wt2)
{
    int b = blockIdx.x, k = threadIdx.x;
    const float* W = (b < D) ? W1 : W2;
    short* Wt = (b < D) ? Wt1 : Wt2;
    int n = b & (D - 1);
    Wt[n * D + k] = f2b(W[k * D + n]);
}

// ---------- MFMA GEMM: C[M,128] = A[M,128] @ W[128,128] (bf16 internally) ----------
// block = 256 thr = 4 waves; tile 64 x 128, full K=128
// buildmode=1: A rows gathered from embedding tables (layer-1 concat fused)
__global__ __launch_bounds__(256) void gemm_mfma(
    const float* __restrict__ A, const short* __restrict__ Wt,
    float* __restrict__ C, int buildmode,
    const int* __restrict__ ent_feature, const float* __restrict__ gw,
    const float* __restrict__ aw, const float* __restrict__ lw,
    const float* __restrict__ idemb, int num_ent)
{
    __shared__ short sA[64 * D];    // 16 KB, 16B granules XOR-swizzled by row&7
    __shared__ short sW[D * D];     // 32 KB, Wt[n][k] bf16, same swizzle

    const int t = threadIdx.x;
    const long row0 = (long)blockIdx.x * 64;

    // ---- stage A tile: 1 thread = 1 row-quarter (32 floats) ----
    {
        int srow = t >> 2;           // 0..63
        int q = t & 3;               // k-quarter
        long grow = row0 + srow;
        const float* srcp;
        if (!buildmode) {
            srcp = A + grow * D;
        } else {
            if (grow < num_ent)               srcp = idemb + grow * D;
            else if (grow < 2L * num_ent)     srcp = gw + (long)ent_feature[(grow - num_ent) * 3 + 0] * D;
            else if (grow < 3L * num_ent)     srcp = aw + (long)ent_feature[(grow - 2L * num_ent) * 3 + 1] * D;
            else                              srcp = lw + (long)ent_feature[(grow - 3L * num_ent) * 3 + 2] * D;
        }
        const float4* p4 = (const float4*)srcp + q * 8;
        float v[32];
        #pragma unroll
        for (int j = 0; j < 8; ++j) {
            float4 f = p4[j];
            v[j * 4 + 0] = f.x; v[j * 4 + 1] = f.y; v[j * 4 + 2] = f.z; v[j * 4 + 3] = f.w;
        }
        #pragma unroll
        for (int jb = 0; jb < 4; ++jb) {
            short8 blk;
            #pragma unroll
            for (int e = 0; e < 8; ++e) blk[e] = f2b(v[jb * 8 + e]);
            int kb = (q * 4 + jb) ^ (srow & 7);
            *(short8*)&sA[srow * D + kb * 8] = blk;
        }
    }

    // ---- stage Wt: 2048 16B-granules, coalesced read, swizzled write ----
    {
        #pragma unroll
        for (int i = 0; i < 8; ++i) {
            int c = t + 256 * i;         // granule id
            int row = c >> 4, kb = c & 15;
            short8 blk = *(const short8*)(Wt + c * 8);
            *(short8*)&sW[row * D + (kb ^ (row & 7)) * 8] = blk;
        }
    }
    __syncthreads();

    // ---- MFMA compute: wave wv owns rows [wv*16, wv*16+16) x all 128 cols ----
    const int wv = t >> 6, lane = t & 63;
    const int cl = lane & 15, kg = lane >> 4;

    short8 a[4];
    #pragma unroll
    for (int ks = 0; ks < 4; ++ks)
        a[ks] = *(const short8*)&sA[(wv * 16 + cl) * D + (((ks * 4 + kg) ^ (cl & 7)) * 8)];

    f32x4 acc[8];
    #pragma unroll
    for (int ct = 0; ct < 8; ++ct) acc[ct] = (f32x4){0.f, 0.f, 0.f, 0.f};

    #pragma unroll
    for (int ct = 0; ct < 8; ++ct) {
        #pragma unroll
        for (int ks = 0; ks < 4; ++ks) {
            short8 b = *(const short8*)&sW[(ct * 16 + cl) * D + (((ks * 4 + kg) ^ (cl & 7)) * 8)];
            acc[ct] = __builtin_amdgcn_mfma_f32_16x16x32_bf16(a[ks], b, acc[ct], 0, 0, 0);
        }
    }

    // ---- epilogue: C/D layout col=lane&15, row=(lane>>4)*4+j ----
    float* Cp = C + (row0 + wv * 16 + kg * 4) * D;
    #pragma unroll
    for (int ct = 0; ct < 8; ++ct)
        #pragma unroll
        for (int j = 0; j < 4; ++j)
            Cp[j * D + ct * 16 + cl] = acc[ct][j];
}

// ---------- tiny GEMM: out[rows,128] = R[rows,128] @ W[128,128] ----------
__global__ void small_gemm(const float* __restrict__ R, const float* __restrict__ W,
                           float* __restrict__ out)
{
    int r = blockIdx.x, c = threadIdx.x;
    float s = 0.f;
    for (int k = 0; k < D; ++k) s = fmaf(R[r * D + k], W[k * D + c], s);
    out[r * D + c] = s;
}

// ---------- CSR build ----------
__global__ __launch_bounds__(256) void hist_deg(const int* __restrict__ dst,
                                                int* __restrict__ deg, int E_)
{
    int i = blockIdx.x * 256 + threadIdx.x;
    if (i < E_) atomicAdd(&deg[dst[i]], 1);
}

__global__ __launch_bounds__(256) void scan_local(const int* __restrict__ deg,
                                                  int* __restrict__ offs,
                                                  int* __restrict__ partial, int n)
{
    __shared__ int lds[256];
    int b = blockIdx.x, t = threadIdx.x;
    int base = b * 1024;
    int v[4]; int s = 0;
    #pragma unroll
    for (int j = 0; j < 4; ++j) {
        int idx = base + t * 4 + j;
        v[j] = idx < n ? deg[idx] : 0;
        s += v[j];
    }
    lds[t] = s;
    __syncthreads();
    int mysum = s;
    for (int off = 1; off < 256; off <<= 1) {
        int o = t >= off ? lds[t - off] : 0;
        __syncthreads();
        lds[t] += o;
        __syncthreads();
    }
    int excl = lds[t] - mysum;
    if (t == 255) partial[b] = lds[255];
    int run = excl;
    #pragma unroll
    for (int j = 0; j < 4; ++j) {
        int idx = base + t * 4 + j;
        if (idx < n) offs[idx] = run;
        run += v[j];
    }
}

__global__ void scan_partials(int* __restrict__ partial, int nb, int* __restrict__ offs, int n)
{
    if (threadIdx.x == 0 && blockIdx.x == 0) {
        int run = 0;
        for (int i = 0; i < nb; ++i) { int v = partial[i]; partial[i] = run; run += v; }
        offs[n] = run;
    }
}

__global__ __launch_bounds__(256) void scan_add(int* __restrict__ offs,
                                                const int* __restrict__ partial, int n)
{
    int idx = blockIdx.x * 256 + threadIdx.x;
    if (idx < n) offs[idx] += partial[idx >> 10];
}

__global__ __launch_bounds__(256) void scatter_edges(
    const int* __restrict__ src, const int* __restrict__ dst, const int* __restrict__ etype,
    const int* __restrict__ offs, int* __restrict__ cursor,
    int* __restrict__ sorted, int E_)
{
    int i = blockIdx.x * 256 + threadIdx.x;
    if (i >= E_) return;
    int d = dst[i];
    int pos = offs[d] + atomicAdd(&cursor[d], 1);
    sorted[pos] = src[i] | (etype[i] << 18);
}

// ---------- fused per-node aggregation: score + online softmax + accum + tanh ----------
__global__ __launch_bounds__(256) void agg_node(
    const int* __restrict__ offs, const int* __restrict__ sedge,
    const float* __restrict__ xW, const float* __restrict__ rW,
    const float* __restrict__ att, float* __restrict__ outx, int Nn)
{
    int wid = threadIdx.x >> 6;
    int lane = threadIdx.x & 63;
    long node = (long)blockIdx.x * 4 + wid;
    if (node >= Nn) return;
    int h = lane >> 4;     // head
    int w = lane & 15;     // position within head (covers 2 floats of 32)

    float2 aq = *(const float2*)(att + h * 64 + 2 * w);
    float2 am = *(const float2*)(att + h * 64 + 32 + 2 * w);
    float2 q  = *(const float2*)(xW + node * D + 2 * lane);

    float qd = q.x * aq.x + q.y * aq.y;
    qd += __shfl_xor(qd, 1);
    qd += __shfl_xor(qd, 2);
    qd += __shfl_xor(qd, 4);
    qd += __shfl_xor(qd, 8);

    int e0 = offs[node], e1 = offs[node + 1];
    float mrun = -INFINITY, srun = 0.f;
    float ax = 0.f, ay = 0.f;

    for (int i = e0; i < e1; ++i) {
        int p  = sedge[i];
        int s  = p & 0x3FFFF;
        int et = p >> 18;
        float2 mv = *(const float2*)(xW + (long)s * D + 2 * lane);
        float2 rv = *(const float2*)(rW + (long)et * D + 2 * lane);
        mv.x += rv.x; mv.y += rv.y;
        float md = mv.x * am.x + mv.y * am.y;
        md += __shfl_xor(md, 1);
        md += __shfl_xor(md, 2);
        md += __shfl_xor(md, 4);
        md += __shfl_xor(md, 8);
        float sc = qd + md;
        sc = sc > 0.f ? sc : 0.2f * sc;          // leaky_relu 0.2
        float nm = fmaxf(mrun, sc);
        float scale = __expf(mrun - nm);
        float we = __expf(sc - nm);
        srun = srun * scale + we;
        ax = ax * scale + we * mv.x;
        ay = ay * scale + we * mv.y;
        mrun = nm;
    }
    float inv = 1.0f / (srun + 1e-16f);
    float2 o;
    o.x = tanhf(ax * inv);
    o.y = tanhf(ay * inv);
    *(float2*)(outx + node * D + 2 * lane) = o;
}

// ---------- row gather ----------
__global__ void gather_rows(const int* __restrict__ idx, const float* __restrict__ srcm,
                            float* __restrict__ dstm, int b)
{
    long i = (long)blockIdx.x * 256 + threadIdx.x;
    if (i >= (long)b * 32) return;
    long row = i >> 5;
    int q = (int)(i & 31);
    ((float4*)dstm)[i] = ((const float4*)(srcm + (long)idx[row] * D))[q];
}

extern "C" void kernel_launch(void* const* d_in, const int* in_sizes, int n_in,
                              void* d_out, int out_size, void* d_ws, size_t ws_size,
                              hipStream_t stream)
{
    const int*   sub        = (const int*)d_in[0];
    const int*   rel        = (const int*)d_in[1];
    const int*   edge_index = (const int*)d_in[2];
    const int*   edge_type  = (const int*)d_in[3];
    const int*   ent_feat   = (const int*)d_in[4];
    const float* gw         = (const float*)d_in[5];
    const float* aw         = (const float*)d_in[6];
    const float* lw         = (const float*)d_in[7];
    const float* idemb      = (const float*)d_in[8];
    const float* init_rel   = (const float*)d_in[9];
    const float* W1         = (const float*)d_in[10];
    const float* Wr1        = (const float*)d_in[11];
    const float* att1       = (const float*)d_in[12];
    const float* W2         = (const float*)d_in[13];
    const float* Wr2        = (const float*)d_in[14];
    const float* att2       = (const float*)d_in[15];

    const int  Bn      = in_sizes[0];
    const int  E_      = in_sizes[3];
    const int  num_ent = in_sizes[4] / 3;
    const long Nn      = 4L * num_ent;
    const int  nrel    = in_sizes[9] / D;

    const int* srcp = edge_index;
    const int* dstp = edge_index + E_;

    float* out_sub = (float*)d_out;
    float* out_rel = out_sub + (long)Bn * D;
    float* out_x   = out_rel + (long)Bn * D;   // N x 128 final x

    float* Xbuf   = (float*)d_ws;              // N x 128 (xW scratch)
    int*   offs   = (int*)(Xbuf + Nn * D);     // N+1
    int*   deg    = offs + (Nn + 1);           // N (also cursor)
    int*   sorted = deg + Nn;                  // E
    int*   partial= sorted + E_;               // <=1024 block partials
    float* rWb    = (float*)(partial + 1024);  // nrel x 128
    float* r1     = rWb + (long)nrel * D;
    float* r2     = r1 + (long)nrel * D;
    short* Wt1    = (short*)(r2 + (long)nrel * D);  // 128x128 bf16
    short* Wt2    = Wt1 + D * D;

    dim3 blk(256);
    int gemm_blocks  = (int)(Nn / 64);
    int e_blocks     = (E_ + 255) / 256;
    int agg_blocks   = (int)((Nn + 3) / 4);
    int gat_blocks   = (int)(((long)Bn * 32 + 255) / 256);
    int scan_blocks  = (int)((Nn + 1023) / 1024);
    int sadd_blocks  = (int)((Nn + 255) / 256);

    // ---------------- weight transpose (both layers) ----------------
    wtrans<<<256, D, 0, stream>>>(W1, W2, Wt1, Wt2);

    // ---------------- CSR build (by dst) ----------------
    hipMemsetAsync(deg, 0, Nn * sizeof(int), stream);
    hist_deg<<<e_blocks, blk, 0, stream>>>(dstp, deg, E_);
    scan_local<<<scan_blocks, blk, 0, stream>>>(deg, offs, partial, (int)Nn);
    scan_partials<<<1, 64, 0, stream>>>(partial, scan_blocks, offs, (int)Nn);
    scan_add<<<sadd_blocks, blk, 0, stream>>>(offs, partial, (int)Nn);
    hipMemsetAsync(deg, 0, Nn * sizeof(int), stream);   // reuse as cursor
    scatter_edges<<<e_blocks, blk, 0, stream>>>(srcp, dstp, edge_type, offs, deg, sorted, E_);

    // ---------------- Layer 1 ----------------
    gemm_mfma<<<gemm_blocks, blk, 0, stream>>>(nullptr, Wt1, Xbuf, 1,
                                               ent_feat, gw, aw, lw, idemb, num_ent);
    small_gemm<<<nrel, D, 0, stream>>>(init_rel, W1, rWb);
    small_gemm<<<nrel, D, 0, stream>>>(init_rel, Wr1, r1);
    agg_node<<<agg_blocks, blk, 0, stream>>>(offs, sorted, Xbuf, rWb, att1, out_x, (int)Nn);

    // ---------------- Layer 2 ----------------
    gemm_mfma<<<gemm_blocks, blk, 0, stream>>>(out_x, Wt2, Xbuf, 0,
                                               nullptr, nullptr, nullptr, nullptr, nullptr, num_ent);
    small_gemm<<<nrel, D, 0, stream>>>(r1, W2, rWb);
    small_gemm<<<nrel, D, 0, stream>>>(r1, Wr2, r2);
    agg_node<<<agg_blocks, blk, 0, stream>>>(offs, sorted, Xbuf, rWb, att2, out_x, (int)Nn);

    // ---------------- outputs ----------------
    gather_rows<<<gat_blocks, blk, 0, stream>>>(sub, out_x, out_sub, Bn);
    gather_rows<<<gat_blocks, blk, 0, stream>>>(rel, r2, out_rel, Bn);
}

// Round 4
// 392.450 us; speedup vs baseline: 23.5030x; 1.0757x over previous
//
#include <hip/hip_runtime.h>

#define D 128
#define HEADS 4

typedef __attribute__((ext_vector_type(8))) short short8;
typedef __attribute__((ext_vector_type(4))) float f32x4;

// f32 -> bf16 (round to nearest even), bit pattern in short
__device__ __forceinline__ short f2b(float f) {
    unsigned u = __float_as_uint(f);
    unsigned r = (u + 0x7FFFu + ((u >> 16) & 1u)) >> 16;
    return (short)r;
}

// ---------- W transpose to bf16: Wt[n][k] = bf16(W[k][n]) ----------
__global__ void wtrans(const float* __restrict__ W1, const float* __restrict__ W2,
                       short* __restrict__ Wt1, short* __restrict__ Wt2)
{
    int b = blockIdx.x, k = threadIdx.x;
    const float* W = (b < D) ? W1 : W2;
    short* Wt = (b < D) ? Wt1 : Wt2;
    int n = b & (D - 1);
    Wt[n * D + k] = f2b(W[k * D + n]);
}

// ---------- MFMA GEMM: C[M,128](bf16) = A[M,128] @ W[128,128] ----------
// block = 256 thr = 4 waves; tile 64 x 128, full K=128
// buildmode 1: A rows gathered f32 from embedding tables (layer-1 concat fused)
// buildmode 2: A rows are bf16 (ushort) rows
__global__ __launch_bounds__(256) void gemm_mfma(
    const unsigned short* __restrict__ Ab, const short* __restrict__ Wt,
    unsigned short* __restrict__ C, int buildmode,
    const int* __restrict__ ent_feature, const float* __restrict__ gw,
    const float* __restrict__ aw, const float* __restrict__ lw,
    const float* __restrict__ idemb, int num_ent)
{
    __shared__ short sA[64 * D];    // 16 KB, 16B granules XOR-swizzled by row&7
    __shared__ short sW[D * D];     // 32 KB

    const int t = threadIdx.x;
    const long row0 = (long)blockIdx.x * 64;

    // ---- stage A tile: 1 thread = 1 row-quarter (32 elems) ----
    {
        int srow = t >> 2;           // 0..63
        int q = t & 3;               // k-quarter
        long grow = row0 + srow;
        if (buildmode == 2) {
            const short8* p8 = (const short8*)(Ab + grow * D);
            #pragma unroll
            for (int jb = 0; jb < 4; ++jb) {
                short8 blk = p8[q * 4 + jb];
                int kb = (q * 4 + jb) ^ (srow & 7);
                *(short8*)&sA[srow * D + kb * 8] = blk;
            }
        } else {
            const float* srcp;
            if (grow < num_ent)               srcp = idemb + grow * D;
            else if (grow < 2L * num_ent)     srcp = gw + (long)ent_feature[(grow - num_ent) * 3 + 0] * D;
            else if (grow < 3L * num_ent)     srcp = aw + (long)ent_feature[(grow - 2L * num_ent) * 3 + 1] * D;
            else                              srcp = lw + (long)ent_feature[(grow - 3L * num_ent) * 3 + 2] * D;
            const float4* p4 = (const float4*)srcp + q * 8;
            float v[32];
            #pragma unroll
            for (int j = 0; j < 8; ++j) {
                float4 f = p4[j];
                v[j * 4 + 0] = f.x; v[j * 4 + 1] = f.y; v[j * 4 + 2] = f.z; v[j * 4 + 3] = f.w;
            }
            #pragma unroll
            for (int jb = 0; jb < 4; ++jb) {
                short8 blk;
                #pragma unroll
                for (int e = 0; e < 8; ++e) blk[e] = f2b(v[jb * 8 + e]);
                int kb = (q * 4 + jb) ^ (srow & 7);
                *(short8*)&sA[srow * D + kb * 8] = blk;
            }
        }
    }

    // ---- stage Wt: coalesced read, swizzled write ----
    {
        #pragma unroll
        for (int i = 0; i < 8; ++i) {
            int c = t + 256 * i;         // granule id
            int row = c >> 4, kb = c & 15;
            short8 blk = *(const short8*)(Wt + c * 8);
            *(short8*)&sW[row * D + (kb ^ (row & 7)) * 8] = blk;
        }
    }
    __syncthreads();

    // ---- MFMA: wave wv owns rows [wv*16, wv*16+16) x all 128 cols ----
    const int wv = t >> 6, lane = t & 63;
    const int cl = lane & 15, kg = lane >> 4;

    short8 a[4];
    #pragma unroll
    for (int ks = 0; ks < 4; ++ks)
        a[ks] = *(const short8*)&sA[(wv * 16 + cl) * D + (((ks * 4 + kg) ^ (cl & 7)) * 8)];

    f32x4 acc[8];
    #pragma unroll
    for (int ct = 0; ct < 8; ++ct) acc[ct] = (f32x4){0.f, 0.f, 0.f, 0.f};

    #pragma unroll
    for (int ct = 0; ct < 8; ++ct) {
        #pragma unroll
        for (int ks = 0; ks < 4; ++ks) {
            short8 b = *(const short8*)&sW[(ct * 16 + cl) * D + (((ks * 4 + kg) ^ (cl & 7)) * 8)];
            acc[ct] = __builtin_amdgcn_mfma_f32_16x16x32_bf16(a[ks], b, acc[ct], 0, 0, 0);
        }
    }

    // ---- epilogue: C/D layout col=lane&15, row=(lane>>4)*4+j; store bf16 ----
    unsigned short* Cp = C + (row0 + wv * 16 + kg * 4) * D;
    #pragma unroll
    for (int ct = 0; ct < 8; ++ct)
        #pragma unroll
        for (int j = 0; j < 4; ++j)
            Cp[j * D + ct * 16 + cl] = (unsigned short)f2b(acc[ct][j]);
}

// ---------- tiny GEMM: out[rows,128] = R[rows,128] @ W[128,128] (f32) ----------
__global__ void small_gemm(const float* __restrict__ R, const float* __restrict__ W,
                           float* __restrict__ out)
{
    int r = blockIdx.x, c = threadIdx.x;
    float s = 0.f;
    for (int k = 0; k < D; ++k) s = fmaf(R[r * D + k], W[k * D + c], s);
    out[r * D + c] = s;
}

// ---------- CSR build ----------
__global__ __launch_bounds__(256) void hist_deg(const int* __restrict__ dst,
                                                int* __restrict__ deg, int E_)
{
    int i = blockIdx.x * 256 + threadIdx.x;
    if (i < E_) atomicAdd(&deg[dst[i]], 1);
}

__global__ __launch_bounds__(256) void scan_local(const int* __restrict__ deg,
                                                  int* __restrict__ offs,
                                                  int* __restrict__ partial, int n)
{
    __shared__ int lds[256];
    int b = blockIdx.x, t = threadIdx.x;
    int base = b * 1024;
    int v[4]; int s = 0;
    #pragma unroll
    for (int j = 0; j < 4; ++j) {
        int idx = base + t * 4 + j;
        v[j] = idx < n ? deg[idx] : 0;
        s += v[j];
    }
    lds[t] = s;
    __syncthreads();
    int mysum = s;
    for (int off = 1; off < 256; off <<= 1) {
        int o = t >= off ? lds[t - off] : 0;
        __syncthreads();
        lds[t] += o;
        __syncthreads();
    }
    int excl = lds[t] - mysum;
    if (t == 255) partial[b] = lds[255];
    int run = excl;
    #pragma unroll
    for (int j = 0; j < 4; ++j) {
        int idx = base + t * 4 + j;
        if (idx < n) offs[idx] = run;
        run += v[j];
    }
}

__global__ void scan_partials(int* __restrict__ partial, int nb, int* __restrict__ offs, int n)
{
    if (threadIdx.x == 0 && blockIdx.x == 0) {
        int run = 0;
        for (int i = 0; i < nb; ++i) { int v = partial[i]; partial[i] = run; run += v; }
        offs[n] = run;
    }
}

__global__ __launch_bounds__(256) void scan_add(int* __restrict__ offs,
                                                const int* __restrict__ partial, int n)
{
    int idx = blockIdx.x * 256 + threadIdx.x;
    if (idx < n) offs[idx] += partial[idx >> 10];
}

__global__ __launch_bounds__(256) void scatter_edges(
    const int* __restrict__ src, const int* __restrict__ dst, const int* __restrict__ etype,
    const int* __restrict__ offs, int* __restrict__ cursor,
    int* __restrict__ sorted, int E_)
{
    int i = blockIdx.x * 256 + threadIdx.x;
    if (i >= E_) return;
    int d = dst[i];
    int pos = offs[d] + atomicAdd(&cursor[d], 1);
    sorted[pos] = src[i] | (etype[i] << 18);
}

// ---------- fused per-node aggregation (bf16 xW), 1-deep pipelined edge loop ----------
// one 64-lane wave per node; lane l covers elems [2l, 2l+1]; head = l>>4
// out_bf16: 1 -> write bf16 row, 0 -> write f32 row
__global__ __launch_bounds__(256) void agg_node(
    const int* __restrict__ offs, const int* __restrict__ sedge,
    const unsigned short* __restrict__ xWb, const float* __restrict__ rW,
    const float* __restrict__ att, void* __restrict__ outx, int out_bf16, int Nn)
{
    int wid = threadIdx.x >> 6;
    int lane = threadIdx.x & 63;
    long node = (long)blockIdx.x * 4 + wid;
    if (node >= Nn) return;
    int h = lane >> 4;     // head
    int w = lane & 15;

    float2 aq = *(const float2*)(att + h * 64 + 2 * w);
    float2 am = *(const float2*)(att + h * 64 + 32 + 2 * w);

    unsigned qb = *(const unsigned*)(xWb + node * D + 2 * lane);
    float qx = __uint_as_float(qb << 16);
    float qy = __uint_as_float(qb & 0xFFFF0000u);

    float qd = qx * aq.x + qy * aq.y;
    qd += __shfl_xor(qd, 1);
    qd += __shfl_xor(qd, 2);
    qd += __shfl_xor(qd, 4);
    qd += __shfl_xor(qd, 8);

    int e0 = offs[node], e1 = offs[node + 1];
    float mrun = -INFINITY, srun = 0.f;
    float ax = 0.f, ay = 0.f;

    if (e0 < e1) {
        int pcur = sedge[e0];
        unsigned mvb = *(const unsigned*)(xWb + (long)(pcur & 0x3FFFF) * D + 2 * lane);
        for (int i = e0; i < e1; ++i) {
            int pnext = 0; unsigned mvb_next = 0;
            bool has = (i + 1 < e1);
            if (has) {
                pnext = sedge[i + 1];
                mvb_next = *(const unsigned*)(xWb + (long)(pnext & 0x3FFFF) * D + 2 * lane);
            }
            int et = pcur >> 18;
            float2 rv = *(const float2*)(rW + (long)et * D + 2 * lane);
            float mx = __uint_as_float(mvb << 16) + rv.x;
            float my = __uint_as_float(mvb & 0xFFFF0000u) + rv.y;
            float md = mx * am.x + my * am.y;
            md += __shfl_xor(md, 1);
            md += __shfl_xor(md, 2);
            md += __shfl_xor(md, 4);
            md += __shfl_xor(md, 8);
            float sc = qd + md;
            sc = sc > 0.f ? sc : 0.2f * sc;          // leaky_relu 0.2
            float nm = fmaxf(mrun, sc);
            float scale = __expf(mrun - nm);
            float we = __expf(sc - nm);
            srun = srun * scale + we;
            ax = ax * scale + we * mx;
            ay = ay * scale + we * my;
            mrun = nm;
            pcur = pnext; mvb = mvb_next;
        }
    }
    float inv = 1.0f / (srun + 1e-16f);
    float ox = tanhf(ax * inv);
    float oy = tanhf(ay * inv);
    if (out_bf16) {
        unsigned pk = ((unsigned)(unsigned short)f2b(oy) << 16) | (unsigned short)f2b(ox);
        *(unsigned*)((unsigned short*)outx + node * D + 2 * lane) = pk;
    } else {
        float2 o; o.x = ox; o.y = oy;
        *(float2*)((float*)outx + node * D + 2 * lane) = o;
    }
}

// ---------- row gather (f32 source) ----------
__global__ void gather_rows(const int* __restrict__ idx, const float* __restrict__ srcm,
                            float* __restrict__ dstm, int b)
{
    long i = (long)blockIdx.x * 256 + threadIdx.x;
    if (i >= (long)b * 32) return;
    long row = i >> 5;
    int q = (int)(i & 31);
    ((float4*)dstm)[i] = ((const float4*)(srcm + (long)idx[row] * D))[q];
}

extern "C" void kernel_launch(void* const* d_in, const int* in_sizes, int n_in,
                              void* d_out, int out_size, void* d_ws, size_t ws_size,
                              hipStream_t stream)
{
    const int*   sub        = (const int*)d_in[0];
    const int*   rel        = (const int*)d_in[1];
    const int*   edge_index = (const int*)d_in[2];
    const int*   edge_type  = (const int*)d_in[3];
    const int*   ent_feat   = (const int*)d_in[4];
    const float* gw         = (const float*)d_in[5];
    const float* aw         = (const float*)d_in[6];
    const float* lw         = (const float*)d_in[7];
    const float* idemb      = (const float*)d_in[8];
    const float* init_rel   = (const float*)d_in[9];
    const float* W1         = (const float*)d_in[10];
    const float* Wr1        = (const float*)d_in[11];
    const float* att1       = (const float*)d_in[12];
    const float* W2         = (const float*)d_in[13];
    const float* Wr2        = (const float*)d_in[14];
    const float* att2       = (const float*)d_in[15];

    const int  Bn      = in_sizes[0];
    const int  E_      = in_sizes[3];
    const int  num_ent = in_sizes[4] / 3;
    const long Nn      = 4L * num_ent;
    const int  nrel    = in_sizes[9] / D;

    const int* srcp = edge_index;
    const int* dstp = edge_index + E_;

    float* out_sub = (float*)d_out;
    float* out_rel = out_sub + (long)Bn * D;
    float* out_x   = out_rel + (long)Bn * D;   // N x 128 final x (f32)

    unsigned short* xWb = (unsigned short*)d_ws;       // N x 128 bf16
    unsigned short* x1b = xWb + Nn * D;                // N x 128 bf16
    int*   offs   = (int*)(x1b + Nn * D);              // N+1
    int*   deg    = offs + (Nn + 1);                   // N (also cursor)
    int*   sorted = deg + Nn;                          // E
    int*   partial= sorted + E_;                       // block partials
    float* rWb    = (float*)(partial + 1024);          // nrel x 128
    float* r1     = rWb + (long)nrel * D;
    float* r2     = r1 + (long)nrel * D;
    short* Wt1    = (short*)(r2 + (long)nrel * D);     // 128x128 bf16
    short* Wt2    = Wt1 + D * D;

    dim3 blk(256);
    int gemm_blocks  = (int)(Nn / 64);
    int e_blocks     = (E_ + 255) / 256;
    int agg_blocks   = (int)((Nn + 3) / 4);
    int gat_blocks   = (int)(((long)Bn * 32 + 255) / 256);
    int scan_blocks  = (int)((Nn + 1023) / 1024);
    int sadd_blocks  = (int)((Nn + 255) / 256);

    // ---------------- weight transpose ----------------
    wtrans<<<256, D, 0, stream>>>(W1, W2, Wt1, Wt2);

    // ---------------- CSR build (by dst) ----------------
    hipMemsetAsync(deg, 0, Nn * sizeof(int), stream);
    hist_deg<<<e_blocks, blk, 0, stream>>>(dstp, deg, E_);
    scan_local<<<scan_blocks, blk, 0, stream>>>(deg, offs, partial, (int)Nn);
    scan_partials<<<1, 64, 0, stream>>>(partial, scan_blocks, offs, (int)Nn);
    scan_add<<<sadd_blocks, blk, 0, stream>>>(offs, partial, (int)Nn);
    hipMemsetAsync(deg, 0, Nn * sizeof(int), stream);   // reuse as cursor
    scatter_edges<<<e_blocks, blk, 0, stream>>>(srcp, dstp, edge_type, offs, deg, sorted, E_);

    // ---------------- Layer 1 ----------------
    gemm_mfma<<<gemm_blocks, blk, 0, stream>>>(nullptr, Wt1, xWb, 1,
                                               ent_feat, gw, aw, lw, idemb, num_ent);
    small_gemm<<<nrel, D, 0, stream>>>(init_rel, W1, rWb);
    small_gemm<<<nrel, D, 0, stream>>>(init_rel, Wr1, r1);
    agg_node<<<agg_blocks, blk, 0, stream>>>(offs, sorted, xWb, rWb, att1, x1b, 1, (int)Nn);

    // ---------------- Layer 2 ----------------
    gemm_mfma<<<gemm_blocks, blk, 0, stream>>>(x1b, Wt2, xWb, 2,
                                               nullptr, nullptr, nullptr, nullptr, nullptr, num_ent);
    small_gemm<<<nrel, D, 0, stream>>>(r1, W2, rWb);
    small_gemm<<<nrel, D, 0, stream>>>(r1, Wr2, r2);
    agg_node<<<agg_blocks, blk, 0, stream>>>(offs, sorted, xWb, rWb, att2, out_x, 0, (int)Nn);

    // ---------------- outputs ----------------
    gather_rows<<<gat_blocks, blk, 0, stream>>>(sub, out_x, out_sub, Bn);
    gather_rows<<<gat_blocks, blk, 0, stream>>>(rel, r2, out_rel, Bn);
}